// Round 9
// baseline (419.359 us; speedup 1.0000x reference)
//
#include <hip/hip_runtime.h>
#include <hip/hip_bf16.h>
#include <stdint.h>

#define B_ROWS 16384
#define D_K    2048
#define C_COLS 1000
#define C_PAD  1024
#define EPS_D2 1e-12f

// GEMM geometry: 256x128 tile, BK=32, 8 waves (4M x 2N), 3-deep LDS ring.
// Grid 512 = exactly 2 blocks/CU (launch_bounds(512,4) + 72KiB LDS) -> the
// whole grid is co-resident, so producer-consumer spin flags cannot deadlock.
#define BM 256
#define BN 128
#define BK 32
#define NT (D_K / BK)          // 64 K-tiles
#define BUFB 24576             // A 16K + B 8K per K-tile
#define NBUF 3                 // ring depth (72 KiB LDS total)

typedef __attribute__((ext_vector_type(8))) short bf16x8;
typedef __attribute__((ext_vector_type(4))) float f32x4;
typedef __attribute__((ext_vector_type(4))) float f4;
typedef __attribute__((ext_vector_type(4))) unsigned u4;

__device__ __forceinline__ void async16(void* lds, const void* g) {
    __builtin_amdgcn_global_load_lds(
        (const __attribute__((address_space(1))) unsigned int*)g,
        (__attribute__((address_space(3))) unsigned int*)lds,
        16, 0, 0);
}

__device__ __forceinline__ unsigned pack2(float a, float b) {
    union { __hip_bfloat162 h; unsigned u; } r;
    r.h = __float22bfloat162_rn(make_float2(a, b));
    return r.u;
}

// Convert one 2048-float row to bf16 (RNE) + fp32 sum-of-squares.
// NT: nontemporal loads/stores (x path: read-once, streamed out).
template<bool NTH>
__device__ __forceinline__ void prep_row(const float* src, __hip_bfloat16* dstp,
                                         float* norm_out, int lane, bool valid) {
    const f4* s4 = (const f4*)src;
    u4* dst = (u4*)dstp;
    f4 v[8];
    if (valid) {
        #pragma unroll
        for (int i = 0; i < 4; i++) {
            if (NTH) {
                v[2 * i]     = __builtin_nontemporal_load(&s4[2 * lane + 128 * i]);
                v[2 * i + 1] = __builtin_nontemporal_load(&s4[2 * lane + 1 + 128 * i]);
            } else {
                v[2 * i]     = s4[2 * lane + 128 * i];
                v[2 * i + 1] = s4[2 * lane + 1 + 128 * i];
            }
        }
    } else {
        #pragma unroll
        for (int i = 0; i < 8; i++) v[i] = (f4)0.f;
    }
    float ss = 0.f;
    #pragma unroll
    for (int i = 0; i < 8; i++)
        ss += v[i].x * v[i].x + v[i].y * v[i].y + v[i].z * v[i].z + v[i].w * v[i].w;
    #pragma unroll
    for (int i = 0; i < 4; i++) {
        u4 p;
        p.x = pack2(v[2 * i].x,     v[2 * i].y);
        p.y = pack2(v[2 * i].z,     v[2 * i].w);
        p.z = pack2(v[2 * i + 1].x, v[2 * i + 1].y);
        p.w = pack2(v[2 * i + 1].z, v[2 * i + 1].w);
        if (NTH) __builtin_nontemporal_store(p, &dst[lane + 64 * i]);
        else     dst[lane + 64 * i] = p;
    }
    #pragma unroll
    for (int off = 32; off > 0; off >>= 1) ss += __shfl_down(ss, off, 64);
    if (lane == 0 && valid) *norm_out = ss;
}

// Fused prep + GEMM. Phase 1: block converts x-rows [id*32, +32) and w-rows
// [id*2, +2); release via agent-scope flags (flagX[panel] 8 contributors,
// flagW 512). Phase 2: acquire own A-panel + all w. Phase 3: r8 gemm.
__global__ __launch_bounds__(512, 4) void dml_fused(
    const float* __restrict__ X, const float* __restrict__ W,
    const float* __restrict__ scales,
    __hip_bfloat16* __restrict__ xb, __hip_bfloat16* __restrict__ wb,
    float* __restrict__ x2, float* __restrict__ w2,
    unsigned* __restrict__ flags,   // [64] panel counters, [64] = w counter
    float* __restrict__ out)
{
    __shared__ __align__(16) char smem[NBUF * BUFB];   // 73728 B

    const int tid  = threadIdx.x;
    const int wave = tid >> 6;
    const int lane = tid & 63;
    const int id   = blockIdx.x;

    // ================= Phase 1: prep =================
    #pragma unroll 1
    for (int rr = 0; rr < 4; ++rr) {
        const int row = id * 32 + wave * 4 + rr;
        prep_row<true>(X + (size_t)row * D_K, xb + (size_t)row * D_K,
                       x2 + row, lane, true);
    }
    if (wave < 2) {
        const int c = id * 2 + wave;
        prep_row<false>(W + (size_t)c * D_K, wb + (size_t)c * D_K,
                        w2 + c, lane, c < C_COLS);
    }
    __syncthreads();   // drains all prep stores (vmcnt(0) before barrier)
    if (tid == 0) {
        __threadfence();  // agent-scope release: L2 writeback
        __hip_atomic_fetch_add(&flags[id >> 3], 1u, __ATOMIC_RELEASE, __HIP_MEMORY_SCOPE_AGENT);
        __hip_atomic_fetch_add(&flags[64],      1u, __ATOMIC_RELEASE, __HIP_MEMORY_SCOPE_AGENT);
    }

    // ================= Phase 2: acquire =================
    const int xcd = id & 7;
    const int j5  = id >> 3;                 // 0..63
    const int m0  = (xcd * 8 + (j5 & 7)) * BM;
    const int n0  = (j5 >> 3) * BN;
    const int pm  = xcd * 8 + (j5 & 7);      // m-panel index

    if (tid == 0) {
        while (__hip_atomic_load(&flags[pm], __ATOMIC_ACQUIRE, __HIP_MEMORY_SCOPE_AGENT) < 8u)
            __builtin_amdgcn_s_sleep(2);
        while (__hip_atomic_load(&flags[64], __ATOMIC_ACQUIRE, __HIP_MEMORY_SCOPE_AGENT) < 512u)
            __builtin_amdgcn_s_sleep(2);
        __threadfence();  // acquire: invalidate stale L2 lines before reads
    }
    __syncthreads();

    // ================= Phase 3: gemm (r8 structure, verbatim) =================
    const int wm = wave >> 1;     // 0..3
    const int wn = wave & 1;      // 0..1

    const __hip_bfloat16* A  = xb;
    const __hip_bfloat16* Bm = wb;

    // staging geometry: A 1024 chunks (2/thread), B 512 chunks (1/thread).
    const int L0 = tid, L1 = tid + 512;
    const int r0 = L0 >> 2, g0 = (L0 & 3) ^ ((r0 >> 1) & 3);
    const int r1 = L1 >> 2, g1 = (L1 & 3) ^ ((r1 >> 1) & 3);
    const int rB = tid >> 2, gB = (tid & 3) ^ ((rB >> 1) & 3);
    const __hip_bfloat16* pA0 = A  + (size_t)(m0 + r0) * D_K + g0 * 8;
    const __hip_bfloat16* pA1 = A  + (size_t)(m0 + r1) * D_K + g1 * 8;
    const __hip_bfloat16* pB  = Bm + (size_t)(n0 + rB) * D_K + gB * 8;
    char* ldA0 = smem + L0 * 16;
    char* ldA1 = smem + L1 * 16;
    char* ldB  = smem + 16384 + tid * 16;

    // fragment read ptrs (swizzled): chunk = fq ^ ((fr>>1)&3)
    const int fr  = lane & 15;
    const int fq  = lane >> 4;
    const int fsw = (fr >> 1) & 3;
    const char* fA = smem + (wm * 64 + fr) * 64 + (fq ^ fsw) * 16;           // + bo
    const char* fB = smem + 16384 + (wn * 64 + fr) * 64 + (fq ^ fsw) * 16;   // + bo

    f32x4 acc[4][4] = {};

    // prologue: stage tiles 0 (buf0) and 1 (buf1); retire tile 0.
    async16(ldA0,        pA0);      async16(ldA1,        pA1);      async16(ldB,        pB);
    async16(ldA0 + BUFB, pA0 + 32); async16(ldA1 + BUFB, pA1 + 32); async16(ldB + BUFB, pB + 32);
    asm volatile("s_waitcnt vmcnt(3)" ::: "memory");
    __builtin_amdgcn_s_barrier();
    __builtin_amdgcn_sched_barrier(0);

    // main loop: tile t reads buf[t%3], stages tile t+2 into buf[(t+2)%3].
    int bo = 0, sbo = 2 * BUFB;
    #pragma unroll 1
    for (int t = 0; t < NT; ++t) {
        if (t + 2 < NT) {
            async16(ldA0 + sbo, pA0 + (t + 2) * BK);
            async16(ldA1 + sbo, pA1 + (t + 2) * BK);
            async16(ldB  + sbo, pB  + (t + 2) * BK);
        }

        bf16x8 b[4], a[4];
        #pragma unroll
        for (int q = 0; q < 4; ++q) b[q] = *(const bf16x8*)(fB + bo + q * 1024);
        #pragma unroll
        for (int i = 0; i < 4; ++i) a[i] = *(const bf16x8*)(fA + bo + i * 1024);
        __builtin_amdgcn_s_setprio(1);
        #pragma unroll
        for (int i = 0; i < 4; ++i)
            #pragma unroll
            for (int q = 0; q < 4; ++q)
                acc[i][q] = __builtin_amdgcn_mfma_f32_16x16x32_bf16(a[i], b[q], acc[i][q], 0, 0, 0);
        __builtin_amdgcn_s_setprio(0);

        if (t < NT - 2)       asm volatile("s_waitcnt vmcnt(3)" ::: "memory");
        else if (t == NT - 2) asm volatile("s_waitcnt vmcnt(0)" ::: "memory");
        if (t < NT - 1) {
            __builtin_amdgcn_s_barrier();
            __builtin_amdgcn_sched_barrier(0);
        }
        bo  = (bo  == 2 * BUFB) ? 0 : bo  + BUFB;
        sbo = (sbo == 2 * BUFB) ? 0 : sbo + BUFB;
    }

    // epilogue: -s*sqrt(max(x2+w2-2*acc, eps)); direct stores.
    const float s = scales[0];
    const int colb = n0 + wn * 64 + fr;
    const int rowb = m0 + wm * 64 + fq * 4;

    float w2v[4];
    #pragma unroll
    for (int q = 0; q < 4; ++q) w2v[q] = w2[colb + q * 16];

    #pragma unroll
    for (int i = 0; i < 4; ++i) {
        float x2v[4];
        #pragma unroll
        for (int r = 0; r < 4; ++r) x2v[r] = x2[rowb + i * 16 + r];
        #pragma unroll
        for (int q = 0; q < 4; ++q) {
            if (colb + q * 16 < C_COLS) {
                float* orow = out + (size_t)(rowb + i * 16) * C_COLS + colb + q * 16;
                #pragma unroll
                for (int r = 0; r < 4; ++r) {
                    float d2 = x2v[r] + w2v[q] - 2.0f * acc[i][q][r];
                    d2 = fmaxf(d2, EPS_D2);
                    orow[(size_t)r * C_COLS] = -s * __builtin_sqrtf(d2);
                }
            }
        }
    }
}

extern "C" void kernel_launch(void* const* d_in, const int* in_sizes, int n_in,
                              void* d_out, int out_size, void* d_ws, size_t ws_size,
                              hipStream_t stream) {
    const float* x      = (const float*)d_in[0];
    const float* w      = (const float*)d_in[1];
    const float* scales = (const float*)d_in[2];
    float* out = (float*)d_out;

    char* ws = (char*)d_ws;
    __hip_bfloat16* xb = (__hip_bfloat16*)ws;                                  // 67,108,864 B
    __hip_bfloat16* wb = (__hip_bfloat16*)(ws + 67108864ull);                  //  4,194,304 B
    float* x2 = (float*)(ws + 71303168ull);                                    //     65,536 B
    float* w2 = (float*)(ws + 71368704ull);                                    //      4,096 B
    unsigned* flags = (unsigned*)(ws + 71372800ull);                           //        260 B

    hipMemsetAsync(flags, 0, 65 * sizeof(unsigned), stream);
    dml_fused<<<dim3(512), dim3(512), 0, stream>>>(x, w, scales, xb, wb, x2, w2, flags, out);
}